// Round 1
// baseline (829.979 us; speedup 1.0000x reference)
//
#include <hip/hip_runtime.h>
#include <hip/hip_bf16.h>

namespace {

constexpr int NB = 4;          // batch
constexpr int CI = 2048;       // in channels
constexpr int CO = 1024;       // out channels
constexpr int HW = 4096;       // H*W
constexpr long SPC = (long)HW * CI;   // per-batch currF elems (channels-last)
constexpr long SPO = (long)HW * CO;   // per-batch [p,o] elems

typedef __attribute__((ext_vector_type(8))) short bf16x8;
typedef __attribute__((ext_vector_type(4))) float f32x4;
typedef __hip_bfloat16 bf16;

__device__ __forceinline__ void g2l16(void* lds, const void* g) {
  __builtin_amdgcn_global_load_lds((const __attribute__((address_space(1))) void*)g,
                                   (__attribute__((address_space(3))) void*)lds,
                                   16, 0, 0);
}

__global__ void zero_k(float* __restrict__ p, int n) {
  int i = blockIdx.x * 256 + threadIdx.x;
  if (i < n) p[i] = 0.f;
}

__global__ void castw_k(const float* __restrict__ s, bf16* __restrict__ d, int n) {
  int i = blockIdx.x * 256 + threadIdx.x;
  if (i < n) d[i] = __float2bfloat16(s[i]);
}

// dst[b,p] += sum over a 128-channel chunk of src[b,c,p]; grid (HW/256, CI/128, NB)
__global__ void nc_sum_k(const float* __restrict__ src, float* __restrict__ dst) {
  int p = blockIdx.x * 256 + threadIdx.x;
  int c0 = blockIdx.y * 128;
  int b = blockIdx.z;
  const float* s = src + ((long)b * CI + c0) * HW + p;
  float a = 0.f;
  #pragma unroll 8
  for (int c = 0; c < 128; ++c) a += s[(long)c * HW];
  atomicAdd(dst + b * HW + p, a);
}

template <typename T> __device__ __forceinline__ T cvt_out(float v);
template <> __device__ __forceinline__ float cvt_out<float>(float v) { return v; }
template <> __device__ __forceinline__ bf16 cvt_out<bf16>(float v) { return __float2bfloat16(v); }

// dst[b, s, r] = src[b, r, s];  grid (R/32, S/32, NB), block 256
template <typename TO>
__global__ void transpose_k(const float* __restrict__ src, TO* __restrict__ dst, int R, int S) {
  __shared__ float tile[32][33];
  int b = blockIdx.z;
  int r0 = blockIdx.x * 32, s0 = blockIdx.y * 32;
  int ts = threadIdx.x & 31, tr = threadIdx.x >> 5;   // tr 0..7
  const float* sp = src + ((long)b * R + r0) * S + s0;
  #pragma unroll
  for (int i = 0; i < 32; i += 8) tile[tr + i][ts] = sp[(long)(tr + i) * S + ts];
  __syncthreads();
  TO* dp = dst + ((long)b * S + s0) * R + r0;
  #pragma unroll
  for (int i = 0; i < 32; i += 8) dp[(long)(tr + i) * R + ts] = cvt_out<TO>(tile[ts][tr + i]);
}

// invden[b,p] = 1/(2048 * sum_{5x5} prev_nc)
__global__ void boxinv_k(const float* __restrict__ nc, float* __restrict__ invden) {
  int i = blockIdx.x * 256 + threadIdx.x;   // over NB*HW
  int b = i >> 12, p = i & 4095;
  int y = p >> 6, x = p & 63;
  float s = 0.f;
  #pragma unroll
  for (int dy = -2; dy <= 2; ++dy) {
    int yy = y + dy;
    if ((unsigned)yy >= 64u) continue;
    #pragma unroll
    for (int dx = -2; dx <= 2; ++dx) {
      int xx = x + dx;
      if ((unsigned)xx >= 64u) continue;
      s += nc[b * HW + yy * 64 + xx];
    }
  }
  invden[i] = 1.f / (2048.f * s);
}

// aligned (channels-last): f32 and bf16 copies. One block per (b,p); threads cover c in float4.
__global__ void align_k(const float* __restrict__ pmcl, const float* __restrict__ nc,
                        const float* __restrict__ invden, const int* __restrict__ body,
                        float* __restrict__ af, bf16* __restrict__ ah) {
  int bp = blockIdx.x;
  int b = bp >> 12, p = bp & 4095;
  int y = p >> 6, x = p & 63;
  int c = threadIdx.x * 4;
  float4 acc = make_float4(0.f, 0.f, 0.f, 0.f);
  if (body[0]) {
    #pragma unroll
    for (int dy = -2; dy <= 2; ++dy) {
      int yy = y + dy;
      if ((unsigned)yy >= 64u) continue;
      #pragma unroll
      for (int dx = -2; dx <= 2; ++dx) {
        int xx = x + dx;
        if ((unsigned)xx >= 64u) continue;
        int sp = yy * 64 + xx;
        float w = nc[b * HW + sp];
        float4 v = *(const float4*)(pmcl + ((long)b * HW + sp) * CO + c);
        acc.x += w * v.x; acc.y += w * v.y; acc.z += w * v.z; acc.w += w * v.w;
      }
    }
    float s = invden[bp];
    acc.x *= s; acc.y *= s; acc.z *= s; acc.w *= s;
  } else {
    acc = *(const float4*)(pmcl + (long)bp * CO + c);
  }
  long o = (long)bp * CO + c;
  *(float4*)(af + o) = acc;
  union { ushort4 u; bf16 h[4]; } pk;
  pk.h[0] = __float2bfloat16(acc.x);
  pk.h[1] = __float2bfloat16(acc.y);
  pk.h[2] = __float2bfloat16(acc.z);
  pk.h[3] = __float2bfloat16(acc.w);
  *(ushort4*)(ah + o) = pk.u;
}

// C[p,o] = sum_k A[p,k]*B[o,k]  (both K-contiguous), m97-style 128x128 tile, BK=32.
// MODE 0: outf = relu(acc + b1 + b2)                              (zt)
// MODE 1: outf = acc + b1                                         (wpart)
// MODE 2: m = relu(acc + b1 + wp); outf = (1-zt)*alig + zt*m      (currM)
// MODE 3: rt = relu(acc + b1 + b2); outh = bf16(alig * rt)        (ar)
template <int MODE>
__global__ __launch_bounds__(256) void gemm128(
    const bf16* __restrict__ A1, long sA1, int ldA1, int K1,
    const bf16* __restrict__ B1, int ldB1,
    const bf16* __restrict__ A2, long sA2, int ldA2, int K2,
    const bf16* __restrict__ B2, int ldB2,
    const float* __restrict__ bias1, const float* __restrict__ bias2,
    const float* __restrict__ wp, const float* __restrict__ ztp,
    const float* __restrict__ alig,
    float* __restrict__ outf, bf16* __restrict__ outh) {
  __shared__ bf16 As[128 * 32];
  __shared__ bf16 Bs[128 * 32];
  const int t = threadIdx.x;
  const int b = blockIdx.z;
  const int bm0 = blockIdx.x * 128;   // p
  const int bn0 = blockIdx.y * 128;   // o
  const int lane = t & 63, wid = t >> 6;
  const int wr = (wid >> 1) * 64, wc = (wid & 1) * 64;  // 2x2 waves of 64x64
  const int fr = lane & 15, kq = lane >> 4;
  const int arow = t >> 2, acol = (t & 3) * 8;
  char* AsB = (char*)As;
  char* BsB = (char*)Bs;

  f32x4 acc[4][4] = {};

  auto ktile = [&](const bf16* Ab, int ldA, const bf16* Bb, int ldB, int K) {
    for (int k0 = 0; k0 < K; k0 += 32) {
      __syncthreads();
      g2l16(AsB + t * 16,        Ab + (long)(bm0 + arow) * ldA + k0 + acol);
      g2l16(AsB + 4096 + t * 16, Ab + (long)(bm0 + 64 + arow) * ldA + k0 + acol);
      g2l16(BsB + t * 16,        Bb + (long)(bn0 + arow) * ldB + k0 + acol);
      g2l16(BsB + 4096 + t * 16, Bb + (long)(bn0 + 64 + arow) * ldB + k0 + acol);
      __syncthreads();
      bf16x8 av[4], bv[4];
      #pragma unroll
      for (int i = 0; i < 4; ++i)
        av[i] = *(const bf16x8*)(As + (wr + i * 16 + fr) * 32 + kq * 8);
      #pragma unroll
      for (int i = 0; i < 4; ++i)
        bv[i] = *(const bf16x8*)(Bs + (wc + i * 16 + fr) * 32 + kq * 8);
      #pragma unroll
      for (int mi = 0; mi < 4; ++mi)
        #pragma unroll
        for (int ni = 0; ni < 4; ++ni)
          acc[mi][ni] = __builtin_amdgcn_mfma_f32_16x16x32_bf16(av[mi], bv[ni], acc[mi][ni], 0, 0, 0);
    }
  };

  ktile(A1 + (long)b * sA1, ldA1, B1, ldB1, K1);
  if (MODE == 0 || MODE == 3) ktile(A2 + (long)b * sA2, ldA2, B2, ldB2, K2);

  const long ob = (long)b * SPO;
  #pragma unroll
  for (int mi = 0; mi < 4; ++mi) {
    const int r0 = bm0 + wr + mi * 16 + (lane >> 4) * 4;
    #pragma unroll
    for (int ni = 0; ni < 4; ++ni) {
      const int col = bn0 + wc + ni * 16 + fr;
      float bsum = bias1[col];
      if (MODE == 0 || MODE == 3) bsum += bias2[col];
      #pragma unroll
      for (int j = 0; j < 4; ++j) {
        const long idx = ob + (long)(r0 + j) * CO + col;
        float v = acc[mi][ni][j] + bsum;
        if (MODE == 0) {
          outf[idx] = fmaxf(v, 0.f);
        } else if (MODE == 1) {
          outf[idx] = v;
        } else if (MODE == 3) {
          float rt = fmaxf(v, 0.f);
          outh[idx] = __float2bfloat16(alig[idx] * rt);
        } else {
          float m = fmaxf(v + wp[idx], 0.f);
          float z = ztp[idx];
          outf[idx] = (1.f - z) * alig[idx] + z * m;
        }
      }
    }
  }
}

}  // namespace

extern "C" void kernel_launch(void* const* d_in, const int* in_sizes, int n_in,
                              void* d_out, int out_size, void* d_ws, size_t ws_size,
                              hipStream_t stream) {
  const float* curr_F = (const float*)d_in[0];
  const float* prev_F = (const float*)d_in[1];
  const float* prev_M = (const float*)d_in[2];
  const float* Wz_w = (const float*)d_in[3];
  const float* Wz_b = (const float*)d_in[4];
  const float* Wr_w = (const float*)d_in[5];
  const float* Wr_b = (const float*)d_in[6];
  const float* W_w  = (const float*)d_in[7];
  const float* W_b  = (const float*)d_in[8];
  const float* Uz_w = (const float*)d_in[9];
  const float* Uz_b = (const float*)d_in[10];
  const float* Ur_w = (const float*)d_in[11];
  const float* Ur_b = (const float*)d_in[12];
  const float* U_w  = (const float*)d_in[13];
  const float* U_b  = (const float*)d_in[14];
  const int* body   = (const int*)d_in[15];
  float* out = (float*)d_out;

  char* ws = (char*)d_ws;
  const size_t M64 = 1ull << 26;  // 64 MiB
  const size_t M32 = 1ull << 25;  // 32 MiB
  // region0: currF bf16 cl -> later currM f32 cl (same byte size)
  bf16*  currF_h   = (bf16*)(ws);
  float* currM_cl  = (float*)(ws);
  // region1: prevM f32 cl -> later zt f32 cl
  float* prevM_cl  = (float*)(ws + M64);
  float* zt        = (float*)(ws + M64);
  float* align_f   = (float*)(ws + 2 * M64);
  bf16*  align_h   = (bf16*)(ws + 3 * M64);
  float* wpart     = (float*)(ws + 3 * M64 + M32);
  bf16*  ar_h      = (bf16*)(ws + 4 * M64 + M32);
  char*  wb        = ws + 4 * M64 + 2 * M32;
  bf16* Wz_h = (bf16*)wb;
  bf16* Wr_h = Wz_h + (size_t)CO * CI;
  bf16* W_h  = Wr_h + (size_t)CO * CI;
  bf16* Uz_h = W_h  + (size_t)CO * CI;
  bf16* Ur_h = Uz_h + (size_t)CO * CO;
  bf16* U_h  = Ur_h + (size_t)CO * CO;
  float* prev_nc = (float*)(U_h + (size_t)CO * CO);
  float* invden  = prev_nc + NB * HW;

  // weights -> bf16
  castw_k<<<dim3((CO * CI) / 256), 256, 0, stream>>>(Wz_w, Wz_h, CO * CI);
  castw_k<<<dim3((CO * CI) / 256), 256, 0, stream>>>(Wr_w, Wr_h, CO * CI);
  castw_k<<<dim3((CO * CI) / 256), 256, 0, stream>>>(W_w,  W_h,  CO * CI);
  castw_k<<<dim3((CO * CO) / 256), 256, 0, stream>>>(Uz_w, Uz_h, CO * CO);
  castw_k<<<dim3((CO * CO) / 256), 256, 0, stream>>>(Ur_w, Ur_h, CO * CO);
  castw_k<<<dim3((CO * CO) / 256), 256, 0, stream>>>(U_w,  U_h,  CO * CO);

  // prev_nc = sum_c prev_F
  zero_k<<<dim3((NB * HW) / 256), 256, 0, stream>>>(prev_nc, NB * HW);
  nc_sum_k<<<dim3(HW / 256, CI / 128, NB), 256, 0, stream>>>(prev_F, prev_nc);

  // transposes to channels-last
  transpose_k<bf16><<<dim3(CI / 32, HW / 32, NB), 256, 0, stream>>>(curr_F, currF_h, CI, HW);
  transpose_k<float><<<dim3(CO / 32, HW / 32, NB), 256, 0, stream>>>(prev_M, prevM_cl, CO, HW);

  boxinv_k<<<dim3((NB * HW) / 256), 256, 0, stream>>>(prev_nc, invden);
  align_k<<<dim3(NB * HW), 256, 0, stream>>>(prevM_cl, prev_nc, invden, body, align_f, align_h);

  dim3 gg(HW / 128, CO / 128, NB);  // (32, 8, 4)
  // zt = relu(Wz@curr + Uz@aligned + biases)   [bn_star is a no-op for B=4]
  gemm128<0><<<gg, 256, 0, stream>>>(currF_h, SPC, CI, CI, Wz_h, CI,
                                     align_h, SPO, CO, CO, Uz_h, CO,
                                     Wz_b, Uz_b, nullptr, nullptr, nullptr, zt, nullptr);
  // ar = bf16(aligned * relu(Wr@curr + Ur@aligned + biases))
  gemm128<3><<<gg, 256, 0, stream>>>(currF_h, SPC, CI, CI, Wr_h, CI,
                                     align_h, SPO, CO, CO, Ur_h, CO,
                                     Wr_b, Ur_b, nullptr, nullptr, align_f, nullptr, ar_h);
  // wpart = W@curr + W_b
  gemm128<1><<<gg, 256, 0, stream>>>(currF_h, SPC, CI, CI, W_h, CI,
                                     nullptr, 0, 0, 0, nullptr, 0,
                                     W_b, nullptr, nullptr, nullptr, nullptr, wpart, nullptr);
  // currM = (1-zt)*aligned + zt*relu(wpart + U@ar + U_b)
  gemm128<2><<<gg, 256, 0, stream>>>(ar_h, SPO, CO, CO, U_h, CO,
                                     nullptr, 0, 0, 0, nullptr, 0,
                                     U_b, nullptr, wpart, zt, align_f, currM_cl, nullptr);

  // [b,p,o] -> [b,o,p]
  transpose_k<float><<<dim3(HW / 32, CO / 32, NB), 256, 0, stream>>>(currM_cl, out, HW, CO);
}

// Round 2
// 665.031 us; speedup vs baseline: 1.2480x; 1.2480x over previous
//
#include <hip/hip_runtime.h>
#include <hip/hip_bf16.h>

namespace {

constexpr int NB = 4;          // batch
constexpr int CI = 2048;       // in channels
constexpr int CO = 1024;       // out channels
constexpr int HW = 4096;       // H*W
constexpr int MTOT = NB * HW;  // 16384 flattened rows
constexpr long SPC = (long)HW * CI;
constexpr long SPO = (long)HW * CO;

typedef __attribute__((ext_vector_type(8))) short bf16x8;
typedef __attribute__((ext_vector_type(4))) float f32x4;
typedef __hip_bfloat16 bf16;

__device__ __forceinline__ void g2l16(void* lds, const void* g) {
  __builtin_amdgcn_global_load_lds((const __attribute__((address_space(1))) void*)g,
                                   (__attribute__((address_space(3))) void*)lds,
                                   16, 0, 0);
}

__global__ void zero_k(float* __restrict__ p, int n) {
  int i = blockIdx.x * 256 + threadIdx.x;
  if (i < n) p[i] = 0.f;
}

__global__ void castw_k(const float* __restrict__ s, bf16* __restrict__ d, int n) {
  int i = blockIdx.x * 256 + threadIdx.x;
  if (i < n) d[i] = __float2bfloat16(s[i]);
}

// dst[b,p] += sum over a 128-channel chunk of src[b,c,p]; grid (HW/256, CI/128, NB)
__global__ void nc_sum_k(const float* __restrict__ src, float* __restrict__ dst) {
  int p = blockIdx.x * 256 + threadIdx.x;
  int c0 = blockIdx.y * 128;
  int b = blockIdx.z;
  const float* s = src + ((long)b * CI + c0) * HW + p;
  float a = 0.f;
  #pragma unroll 8
  for (int c = 0; c < 128; ++c) a += s[(long)c * HW];
  atomicAdd(dst + b * HW + p, a);
}

template <typename T> __device__ __forceinline__ T cvt_out(float v);
template <> __device__ __forceinline__ float cvt_out<float>(float v) { return v; }
template <> __device__ __forceinline__ bf16 cvt_out<bf16>(float v) { return __float2bfloat16(v); }

// dst[b, s, r] = src[b, r, s];  grid (R/32, S/32, NB), block 256
template <typename TO>
__global__ void transpose_k(const float* __restrict__ src, TO* __restrict__ dst, int R, int S) {
  __shared__ float tile[32][33];
  int b = blockIdx.z;
  int r0 = blockIdx.x * 32, s0 = blockIdx.y * 32;
  int ts = threadIdx.x & 31, tr = threadIdx.x >> 5;   // tr 0..7
  const float* sp = src + ((long)b * R + r0) * S + s0;
  #pragma unroll
  for (int i = 0; i < 32; i += 8) tile[tr + i][ts] = sp[(long)(tr + i) * S + ts];
  __syncthreads();
  TO* dp = dst + ((long)b * S + s0) * R + r0;
  #pragma unroll
  for (int i = 0; i < 32; i += 8) dp[(long)(tr + i) * R + ts] = cvt_out<TO>(tile[ts][tr + i]);
}

// invden[b,p] = 1/(2048 * sum_{5x5} prev_nc)
__global__ void boxinv_k(const float* __restrict__ nc, float* __restrict__ invden) {
  int i = blockIdx.x * 256 + threadIdx.x;   // over NB*HW
  int b = i >> 12, p = i & 4095;
  int y = p >> 6, x = p & 63;
  float s = 0.f;
  #pragma unroll
  for (int dy = -2; dy <= 2; ++dy) {
    int yy = y + dy;
    if ((unsigned)yy >= 64u) continue;
    #pragma unroll
    for (int dx = -2; dx <= 2; ++dx) {
      int xx = x + dx;
      if ((unsigned)xx >= 64u) continue;
      s += nc[b * HW + yy * 64 + xx];
    }
  }
  invden[i] = 1.f / (2048.f * s);
}

// aligned (channels-last): f32 and bf16 copies. One block per (b,p); threads cover c in float4.
__global__ void align_k(const float* __restrict__ pmcl, const float* __restrict__ nc,
                        const float* __restrict__ invden, const int* __restrict__ body,
                        float* __restrict__ af, bf16* __restrict__ ah) {
  int bp = blockIdx.x;
  int b = bp >> 12, p = bp & 4095;
  int y = p >> 6, x = p & 63;
  int c = threadIdx.x * 4;
  float4 acc = make_float4(0.f, 0.f, 0.f, 0.f);
  if (body[0]) {
    #pragma unroll
    for (int dy = -2; dy <= 2; ++dy) {
      int yy = y + dy;
      if ((unsigned)yy >= 64u) continue;
      #pragma unroll
      for (int dx = -2; dx <= 2; ++dx) {
        int xx = x + dx;
        if ((unsigned)xx >= 64u) continue;
        int sp = yy * 64 + xx;
        float w = nc[b * HW + sp];
        float4 v = *(const float4*)(pmcl + ((long)b * HW + sp) * CO + c);
        acc.x += w * v.x; acc.y += w * v.y; acc.z += w * v.z; acc.w += w * v.w;
      }
    }
    float s = invden[bp];
    acc.x *= s; acc.y *= s; acc.z *= s; acc.w *= s;
  } else {
    acc = *(const float4*)(pmcl + (long)bp * CO + c);
  }
  long o = (long)bp * CO + c;
  *(float4*)(af + o) = acc;
  union { ushort4 u; bf16 h[4]; } pk;
  pk.h[0] = __float2bfloat16(acc.x);
  pk.h[1] = __float2bfloat16(acc.y);
  pk.h[2] = __float2bfloat16(acc.z);
  pk.h[3] = __float2bfloat16(acc.w);
  *(ushort4*)(ah + o) = pk.u;
}

// ---------------------------------------------------------------------------
// 256x256-tile GEMM, 8 waves (2Mx4N), 4-deep ring of BK=32 subtiles in LDS,
// counted-vmcnt pipeline (T3+T4), swizzled LDS (T2), setprio (T5).
// C[p,o] = sum_k A[p,k]*B[o,k]; A,B K-contiguous bf16.
// LDS buffer b (32 KiB): A-region [0,16K) = 128 lines x 128B (line j = rows
// 2j,2j+1 of 32 bf16 k's each); B-region [16K,32K) same. Storage swizzle:
// S = L ^ ((line&7)<<4); inverse applied to global source (both-sides rule).
// MODE 0: outf = relu(acc + b1 + b2)                              (zt)
// MODE 1: outf = acc + b1                                         (wpart)
// MODE 2: m = relu(acc + b1 + wp); outf = (1-zt)*alig + zt*m      (currM)
// MODE 3: rt = relu(acc + b1 + b2); outh = bf16(alig * rt)        (ar)
// ---------------------------------------------------------------------------
template <int MODE>
__global__ __launch_bounds__(512, 2) void gemm256(
    const bf16* __restrict__ A1, int ldA1, int K1,
    const bf16* __restrict__ B1, int ldB1,
    const bf16* __restrict__ A2, int ldA2, int K2,
    const bf16* __restrict__ B2, int ldB2,
    const float* __restrict__ bias1, const float* __restrict__ bias2,
    const float* __restrict__ wp, const float* __restrict__ ztp,
    const float* __restrict__ alig,
    float* __restrict__ outf, bf16* __restrict__ outh) {
  __shared__ __align__(16) char lds[131072];
  const int t = threadIdx.x, lane = t & 63, wid = t >> 6;
  const int wm = wid >> 2, wn = wid & 3;
  const int m0 = blockIdx.x * 256, n0 = blockIdx.y * 256;
  const int fr = lane & 15, kq = lane >> 4;
  const int nt1 = K1 / 32, nt = nt1 + K2 / 32;

  // --- staging source precompute (inverse swizzle on global address) ---
  // thread covers storage 16B-blocks {wid*128+lane, wid*128+64+lane} of each
  // region; block b: line=b>>3, c3=(b&7)^(line&7) -> row=2*line+(c3>>2),
  // k16=c3&3. Second block = first + 16 rows (same k16).
  const int b0i = (wid << 7) + lane;
  const int line0 = b0i >> 3;
  const int c3 = (b0i & 7) ^ (line0 & 7);
  const int row0 = 2 * line0 + (c3 >> 2);
  const int k16 = c3 & 3;
  const char* pa1 = (const char*)A1 + (((size_t)(m0 + row0) * ldA1 + k16 * 8) << 1);
  const char* pa1h = pa1 + ((size_t)ldA1 << 5);   // +16 rows
  const char* pb1 = (const char*)B1 + (((size_t)(n0 + row0) * ldB1 + k16 * 8) << 1);
  const char* pb1h = pb1 + ((size_t)ldB1 << 5);
  const char* pa2 = (const char*)A2 + (((size_t)(m0 + row0) * ldA2 + k16 * 8) << 1);
  const char* pa2h = pa2 + ((size_t)ldA2 << 5);
  const char* pb2 = (const char*)B2 + (((size_t)(n0 + row0) * ldB2 + k16 * 8) << 1);
  const char* pb2h = pb2 + ((size_t)ldB2 << 5);

  auto STAGE = [&](int s) {
    const char *sa, *sah, *sb, *sbh;
    if (s < nt1) {
      size_t so = (size_t)s << 6;
      sa = pa1 + so; sah = pa1h + so; sb = pb1 + so; sbh = pb1h + so;
    } else {
      size_t so = (size_t)(s - nt1) << 6;
      sa = pa2 + so; sah = pa2h + so; sb = pb2 + so; sbh = pb2h + so;
    }
    char* d = lds + ((s & 3) << 15) + (wid << 11) + (lane << 4);
    g2l16(d, sa);
    g2l16(d + 1024, sah);
    g2l16(d + 16384, sb);
    g2l16(d + 17408, sbh);
  };

  // --- fragment LDS read offsets (swizzled), loop-invariant ---
  int offA[8], offB[4];
  #pragma unroll
  for (int mi = 0; mi < 8; ++mi) {
    int r = (wm << 7) + (mi << 4) + fr;
    int ln = r >> 1;
    int cc = ((r & 1) << 2) | kq;
    offA[mi] = (ln << 7) + ((cc ^ (ln & 7)) << 4);
  }
  #pragma unroll
  for (int ni = 0; ni < 4; ++ni) {
    int r = (wn << 6) + (ni << 4) + fr;
    int ln = r >> 1;
    int cc = ((r & 1) << 2) | kq;
    offB[ni] = 16384 + (ln << 7) + ((cc ^ (ln & 7)) << 4);
  }

  f32x4 acc[8][4] = {};

  STAGE(0); STAGE(1); STAGE(2);

  auto PHASE = [&](int tp, int W, bool dostage) {
    if (dostage) STAGE(tp + 3);
    if (W == 12)      asm volatile("s_waitcnt vmcnt(12)" ::: "memory");
    else if (W == 8)  asm volatile("s_waitcnt vmcnt(8)" ::: "memory");
    else if (W == 4)  asm volatile("s_waitcnt vmcnt(4)" ::: "memory");
    else              asm volatile("s_waitcnt vmcnt(0)" ::: "memory");
    __builtin_amdgcn_s_barrier();
    asm volatile("" ::: "memory");   // keep ds_reads below the barrier
    const char* buf = lds + ((tp & 3) << 15);
    bf16x8 av[8], bv[4];
    #pragma unroll
    for (int mi = 0; mi < 8; ++mi) av[mi] = *(const bf16x8*)(buf + offA[mi]);
    #pragma unroll
    for (int ni = 0; ni < 4; ++ni) bv[ni] = *(const bf16x8*)(buf + offB[ni]);
    __builtin_amdgcn_s_setprio(1);
    #pragma unroll
    for (int mi = 0; mi < 8; ++mi)
      #pragma unroll
      for (int ni = 0; ni < 4; ++ni)
        acc[mi][ni] = __builtin_amdgcn_mfma_f32_16x16x32_bf16(av[mi], bv[ni], acc[mi][ni], 0, 0, 0);
    __builtin_amdgcn_s_setprio(0);
    asm volatile("" ::: "memory");   // keep ds_reads above the barrier
    __builtin_amdgcn_s_barrier();    // frees buf[tp&3] for next phase's STAGE
  };

  for (int tt = 0; tt < nt - 3; ++tt) PHASE(tt, 12, true);
  PHASE(nt - 3, 8, false);
  PHASE(nt - 2, 4, false);
  PHASE(nt - 1, 0, false);

  // --- epilogue ---
  #pragma unroll
  for (int mi = 0; mi < 8; ++mi) {
    const int r0 = m0 + (wm << 7) + (mi << 4) + (kq << 2);
    #pragma unroll
    for (int ni = 0; ni < 4; ++ni) {
      const int col = n0 + (wn << 6) + (ni << 4) + fr;
      float bsum = bias1[col];
      if (MODE == 0 || MODE == 3) bsum += bias2[col];
      #pragma unroll
      for (int j = 0; j < 4; ++j) {
        const size_t idx = (size_t)(r0 + j) * CO + col;
        float v = acc[mi][ni][j] + bsum;
        if (MODE == 0) {
          outf[idx] = fmaxf(v, 0.f);
        } else if (MODE == 1) {
          outf[idx] = v;
        } else if (MODE == 3) {
          float rt = fmaxf(v, 0.f);
          outh[idx] = __float2bfloat16(alig[idx] * rt);
        } else {
          float m = fmaxf(v + wp[idx], 0.f);
          float z = ztp[idx];
          outf[idx] = (1.f - z) * alig[idx] + z * m;
        }
      }
    }
  }
}

}  // namespace

extern "C" void kernel_launch(void* const* d_in, const int* in_sizes, int n_in,
                              void* d_out, int out_size, void* d_ws, size_t ws_size,
                              hipStream_t stream) {
  const float* curr_F = (const float*)d_in[0];
  const float* prev_F = (const float*)d_in[1];
  const float* prev_M = (const float*)d_in[2];
  const float* Wz_w = (const float*)d_in[3];
  const float* Wz_b = (const float*)d_in[4];
  const float* Wr_w = (const float*)d_in[5];
  const float* Wr_b = (const float*)d_in[6];
  const float* W_w  = (const float*)d_in[7];
  const float* W_b  = (const float*)d_in[8];
  const float* Uz_w = (const float*)d_in[9];
  const float* Uz_b = (const float*)d_in[10];
  const float* Ur_w = (const float*)d_in[11];
  const float* Ur_b = (const float*)d_in[12];
  const float* U_w  = (const float*)d_in[13];
  const float* U_b  = (const float*)d_in[14];
  const int* body   = (const int*)d_in[15];
  float* out = (float*)d_out;

  char* ws = (char*)d_ws;
  const size_t M64 = 1ull << 26;  // 64 MiB
  const size_t M32 = 1ull << 25;  // 32 MiB
  // region0: currF bf16 cl -> later currM f32 cl (same byte size)
  bf16*  currF_h   = (bf16*)(ws);
  float* currM_cl  = (float*)(ws);
  // region1: prevM f32 cl -> later zt f32 cl
  float* prevM_cl  = (float*)(ws + M64);
  float* zt        = (float*)(ws + M64);
  float* align_f   = (float*)(ws + 2 * M64);
  bf16*  align_h   = (bf16*)(ws + 3 * M64);
  float* wpart     = (float*)(ws + 3 * M64 + M32);
  bf16*  ar_h      = (bf16*)(ws + 4 * M64 + M32);
  char*  wb        = ws + 4 * M64 + 2 * M32;
  bf16* Wz_h = (bf16*)wb;
  bf16* Wr_h = Wz_h + (size_t)CO * CI;
  bf16* W_h  = Wr_h + (size_t)CO * CI;
  bf16* Uz_h = W_h  + (size_t)CO * CI;
  bf16* Ur_h = Uz_h + (size_t)CO * CO;
  bf16* U_h  = Ur_h + (size_t)CO * CO;
  float* prev_nc = (float*)(U_h + (size_t)CO * CO);
  float* invden  = prev_nc + NB * HW;

  // weights -> bf16
  castw_k<<<dim3((CO * CI) / 256), 256, 0, stream>>>(Wz_w, Wz_h, CO * CI);
  castw_k<<<dim3((CO * CI) / 256), 256, 0, stream>>>(Wr_w, Wr_h, CO * CI);
  castw_k<<<dim3((CO * CI) / 256), 256, 0, stream>>>(W_w,  W_h,  CO * CI);
  castw_k<<<dim3((CO * CO) / 256), 256, 0, stream>>>(Uz_w, Uz_h, CO * CO);
  castw_k<<<dim3((CO * CO) / 256), 256, 0, stream>>>(Ur_w, Ur_h, CO * CO);
  castw_k<<<dim3((CO * CO) / 256), 256, 0, stream>>>(U_w,  U_h,  CO * CO);

  // prev_nc = sum_c prev_F
  zero_k<<<dim3((NB * HW) / 256), 256, 0, stream>>>(prev_nc, NB * HW);
  nc_sum_k<<<dim3(HW / 256, CI / 128, NB), 256, 0, stream>>>(prev_F, prev_nc);

  // transposes to channels-last
  transpose_k<bf16><<<dim3(CI / 32, HW / 32, NB), 256, 0, stream>>>(curr_F, currF_h, CI, HW);
  transpose_k<float><<<dim3(CO / 32, HW / 32, NB), 256, 0, stream>>>(prev_M, prevM_cl, CO, HW);

  boxinv_k<<<dim3((NB * HW) / 256), 256, 0, stream>>>(prev_nc, invden);
  align_k<<<dim3(NB * HW), 256, 0, stream>>>(prevM_cl, prev_nc, invden, body, align_f, align_h);

  dim3 gg(MTOT / 256, CO / 256);  // (64, 4) = 256 workgroups = 1/CU
  // zt = relu(Wz@curr + Uz@aligned + biases)   [bn_star is a no-op for B=4]
  gemm256<0><<<gg, 512, 0, stream>>>(currF_h, CI, CI, Wz_h, CI,
                                     align_h, CO, CO, Uz_h, CO,
                                     Wz_b, Uz_b, nullptr, nullptr, nullptr, zt, nullptr);
  // ar = bf16(aligned * relu(Wr@curr + Ur@aligned + biases))
  gemm256<3><<<gg, 512, 0, stream>>>(currF_h, CI, CI, Wr_h, CI,
                                     align_h, CO, CO, Ur_h, CO,
                                     Wr_b, Ur_b, nullptr, nullptr, align_f, nullptr, ar_h);
  // wpart = W@curr + W_b
  gemm256<1><<<gg, 512, 0, stream>>>(currF_h, CI, CI, W_h, CI,
                                     currF_h, CI, 0, W_h, CI,
                                     W_b, nullptr, nullptr, nullptr, nullptr, wpart, nullptr);
  // currM = (1-zt)*aligned + zt*relu(wpart + U@ar + U_b)
  gemm256<2><<<gg, 512, 0, stream>>>(ar_h, CO, CO, U_h, CO,
                                     ar_h, CO, 0, U_h, CO,
                                     U_b, nullptr, wpart, zt, align_f, currM_cl, nullptr);

  // [b,p,o] -> [b,o,p]
  transpose_k<float><<<dim3(HW / 32, CO / 32, NB), 256, 0, stream>>>(currM_cl, out, HW, CO);
}

// Round 3
// 591.109 us; speedup vs baseline: 1.4041x; 1.1251x over previous
//
#include <hip/hip_runtime.h>
#include <hip/hip_bf16.h>

namespace {

constexpr int NB = 4;          // batch
constexpr int CI = 2048;       // in channels
constexpr int CO = 1024;       // out channels
constexpr int HW = 4096;       // H*W
constexpr int MTOT = NB * HW;  // 16384 flattened rows

typedef __attribute__((ext_vector_type(8))) short bf16x8;
typedef __attribute__((ext_vector_type(4))) float f32x4;
typedef __hip_bfloat16 bf16;

__device__ __forceinline__ void g2l16(void* lds, const void* g) {
  __builtin_amdgcn_global_load_lds((const __attribute__((address_space(1))) void*)g,
                                   (__attribute__((address_space(3))) void*)lds,
                                   16, 0, 0);
}

__global__ void zero_k(float* __restrict__ p, int n) {
  int i = blockIdx.x * 256 + threadIdx.x;
  if (i < n) p[i] = 0.f;
}

// all six weight casts in one launch; y<3 are CI*CO, y>=3 are CO*CO; float4->ushort4
__global__ void castw6_k(const float* s0, const float* s1, const float* s2,
                         const float* s3, const float* s4, const float* s5,
                         bf16* d0, bf16* d1, bf16* d2, bf16* d3, bf16* d4, bf16* d5) {
  int y = blockIdx.y;
  const float* s = (y == 0) ? s0 : (y == 1) ? s1 : (y == 2) ? s2 : (y == 3) ? s3 : (y == 4) ? s4 : s5;
  bf16* d = (y == 0) ? d0 : (y == 1) ? d1 : (y == 2) ? d2 : (y == 3) ? d3 : (y == 4) ? d4 : d5;
  int n4 = ((y < 3) ? CI * CO : CO * CO) >> 2;
  int i = blockIdx.x * 256 + threadIdx.x;
  if (i < n4) {
    float4 v = ((const float4*)s)[i];
    union { ushort4 u; bf16 h[4]; } pk;
    pk.h[0] = __float2bfloat16(v.x);
    pk.h[1] = __float2bfloat16(v.y);
    pk.h[2] = __float2bfloat16(v.z);
    pk.h[3] = __float2bfloat16(v.w);
    ((ushort4*)d)[i] = pk.u;
  }
}

// dst[b,p] += sum over a 128-channel chunk of src[b,c,p]; grid (HW/256, CI/128, NB)
__global__ void nc_sum_k(const float* __restrict__ src, float* __restrict__ dst) {
  int p = blockIdx.x * 256 + threadIdx.x;
  int c0 = blockIdx.y * 128;
  int b = blockIdx.z;
  const float* s = src + ((long)b * CI + c0) * HW + p;
  float a = 0.f;
  #pragma unroll 8
  for (int c = 0; c < 128; ++c) a += s[(long)c * HW];
  atomicAdd(dst + b * HW + p, a);
}

template <typename T> __device__ __forceinline__ T cvt_out(float v);
template <> __device__ __forceinline__ float cvt_out<float>(float v) { return v; }
template <> __device__ __forceinline__ bf16 cvt_out<bf16>(float v) { return __float2bfloat16(v); }

// dst[b, s, r] = src[b, r, s];  grid (R/32, S/32, NB), block 256
template <typename TO>
__global__ void transpose_k(const float* __restrict__ src, TO* __restrict__ dst, int R, int S) {
  __shared__ float tile[32][33];
  int b = blockIdx.z;
  int r0 = blockIdx.x * 32, s0 = blockIdx.y * 32;
  int ts = threadIdx.x & 31, tr = threadIdx.x >> 5;   // tr 0..7
  const float* sp = src + ((long)b * R + r0) * S + s0;
  #pragma unroll
  for (int i = 0; i < 32; i += 8) tile[tr + i][ts] = sp[(long)(tr + i) * S + ts];
  __syncthreads();
  TO* dp = dst + ((long)b * S + s0) * R + r0;
  #pragma unroll
  for (int i = 0; i < 32; i += 8) dp[(long)(tr + i) * R + ts] = cvt_out<TO>(tile[ts][tr + i]);
}

// invden[b,p] = 1/(2048 * sum_{5x5} prev_nc)
__global__ void boxinv_k(const float* __restrict__ nc, float* __restrict__ invden) {
  int i = blockIdx.x * 256 + threadIdx.x;   // over NB*HW
  int b = i >> 12, p = i & 4095;
  int y = p >> 6, x = p & 63;
  float s = 0.f;
  #pragma unroll
  for (int dy = -2; dy <= 2; ++dy) {
    int yy = y + dy;
    if ((unsigned)yy >= 64u) continue;
    #pragma unroll
    for (int dx = -2; dx <= 2; ++dx) {
      int xx = x + dx;
      if ((unsigned)xx >= 64u) continue;
      s += nc[b * HW + yy * 64 + xx];
    }
  }
  invden[i] = 1.f / (2048.f * s);
}

// aligned (channels-last): f32 and bf16 copies. One block per (b,p); threads cover c in float4.
__global__ void align_k(const float* __restrict__ pmcl, const float* __restrict__ nc,
                        const float* __restrict__ invden, const int* __restrict__ body,
                        float* __restrict__ af, bf16* __restrict__ ah) {
  int bp = blockIdx.x;
  int b = bp >> 12, p = bp & 4095;
  int y = p >> 6, x = p & 63;
  int c = threadIdx.x * 4;
  float4 acc = make_float4(0.f, 0.f, 0.f, 0.f);
  if (body[0]) {
    #pragma unroll
    for (int dy = -2; dy <= 2; ++dy) {
      int yy = y + dy;
      if ((unsigned)yy >= 64u) continue;
      #pragma unroll
      for (int dx = -2; dx <= 2; ++dx) {
        int xx = x + dx;
        if ((unsigned)xx >= 64u) continue;
        int sp = yy * 64 + xx;
        float w = nc[b * HW + sp];
        float4 v = *(const float4*)(pmcl + ((long)b * HW + sp) * CO + c);
        acc.x += w * v.x; acc.y += w * v.y; acc.z += w * v.z; acc.w += w * v.w;
      }
    }
    float s = invden[bp];
    acc.x *= s; acc.y *= s; acc.z *= s; acc.w *= s;
  } else {
    acc = *(const float4*)(pmcl + (long)bp * CO + c);
  }
  long o = (long)bp * CO + c;
  *(float4*)(af + o) = acc;
  union { ushort4 u; bf16 h[4]; } pk;
  pk.h[0] = __float2bfloat16(acc.x);
  pk.h[1] = __float2bfloat16(acc.y);
  pk.h[2] = __float2bfloat16(acc.z);
  pk.h[3] = __float2bfloat16(acc.w);
  *(ushort4*)(ah + o) = pk.u;
}

// ---------------------------------------------------------------------------
// 256x256-tile dual-K GEMM, 8 waves (2Mx4N), 4-deep ring of BK=32 subtiles,
// hoisted-read counted-vmcnt pipeline (T3+T4), swizzled LDS (T2), setprio (T5).
// C[p,o] = sum_k A1[p,k]B1[o,k] + sum_k A2[p,k]B2[o,k];  K1=2048, K2=1024.
// Schedule per phase p: {read bv[p] | STAGE(p+3) | vmcnt(8) retires stage p+1 |
// barrier | 32 MFMA on regs | read av[p+1] | barrier}. All MFMA operands are
// in registers before barrier-1 -> LDS reads off the critical path.
// MODE 0: outf = relu(acc + b1 + b2)                              (zt)
// MODE 2: m = relu(acc + b1 + b2); outf = (1-zt)*alig + zt*m      (currM)
// MODE 3: rt = relu(acc + b1 + b2); outh = bf16(aligh * rt)       (ar)
// ---------------------------------------------------------------------------
template <int MODE>
__global__ __launch_bounds__(512, 2) void gemm256(
    const bf16* __restrict__ A1, const bf16* __restrict__ B1,
    const bf16* __restrict__ A2, const bf16* __restrict__ B2,
    const float* __restrict__ bias1, const float* __restrict__ bias2,
    const float* __restrict__ ztp, const float* __restrict__ alig,
    const bf16* __restrict__ aligh,
    float* __restrict__ outf, bf16* __restrict__ outh) {
  constexpr int ldA1 = CI, ldB1 = CI, ldA2 = CO, ldB2 = CO;
  constexpr int NT1 = CI / 32;        // 64
  constexpr int NT = NT1 + CO / 32;   // 96
  __shared__ __align__(16) char lds[131072];
  const int t = threadIdx.x, lane = t & 63, wid = t >> 6;
  const int wm = wid >> 2, wn = wid & 3;
  const int m0 = blockIdx.x * 256, n0 = blockIdx.y * 256;
  const int fr = lane & 15, kq = lane >> 4;

  // --- staging source precompute (inverse swizzle on global address) ---
  const int b0i = (wid << 7) + lane;
  const int line0 = b0i >> 3;
  const int c3 = (b0i & 7) ^ (line0 & 7);
  const int row0 = 2 * line0 + (c3 >> 2);
  const int k16 = c3 & 3;
  const char* pa1 = (const char*)A1 + (((size_t)(m0 + row0) * ldA1 + k16 * 8) << 1);
  const char* pa1h = pa1 + ((size_t)ldA1 << 5);   // +16 rows
  const char* pb1 = (const char*)B1 + (((size_t)(n0 + row0) * ldB1 + k16 * 8) << 1);
  const char* pb1h = pb1 + ((size_t)ldB1 << 5);
  const char* pa2 = (const char*)A2 + (((size_t)(m0 + row0) * ldA2 + k16 * 8) << 1);
  const char* pa2h = pa2 + ((size_t)ldA2 << 5);
  const char* pb2 = (const char*)B2 + (((size_t)(n0 + row0) * ldB2 + k16 * 8) << 1);
  const char* pb2h = pb2 + ((size_t)ldB2 << 5);

  auto STAGE = [&](int s) {
    const char *sa, *sah, *sb, *sbh;
    if (s < NT1) {
      size_t so = (size_t)s << 6;
      sa = pa1 + so; sah = pa1h + so; sb = pb1 + so; sbh = pb1h + so;
    } else {
      size_t so = (size_t)(s - NT1) << 6;
      sa = pa2 + so; sah = pa2h + so; sb = pb2 + so; sbh = pb2h + so;
    }
    char* d = lds + ((s & 3) << 15) + (wid << 11) + (lane << 4);
    g2l16(d, sa);
    g2l16(d + 1024, sah);
    g2l16(d + 16384, sb);
    g2l16(d + 17408, sbh);
  };

  // --- fragment LDS read offsets (swizzled), loop-invariant ---
  int offA[8], offB[4];
  #pragma unroll
  for (int mi = 0; mi < 8; ++mi) {
    int r = (wm << 7) + (mi << 4) + fr;
    int ln = r >> 1;
    int cc = ((r & 1) << 2) | kq;
    offA[mi] = (ln << 7) + ((cc ^ (ln & 7)) << 4);
  }
  #pragma unroll
  for (int ni = 0; ni < 4; ++ni) {
    int r = (wn << 6) + (ni << 4) + fr;
    int ln = r >> 1;
    int cc = ((r & 1) << 2) | kq;
    offB[ni] = 16384 + (ln << 7) + ((cc ^ (ln & 7)) << 4);
  }

  f32x4 acc[8][4] = {};
  bf16x8 avA[8], avB[8], bv[4];

  // prologue: fill ring slots 0..2, make buffer 0 visible, preload av[0]
  STAGE(0); STAGE(1); STAGE(2);
  asm volatile("s_waitcnt vmcnt(8)" ::: "memory");   // stage 0 retired
  __builtin_amdgcn_s_barrier();
  asm volatile("" ::: "memory");
  #pragma unroll
  for (int mi = 0; mi < 8; ++mi) avA[mi] = *(const bf16x8*)(lds + offA[mi]);

#define PHASE(p, AVC, AVN, W, DOSTAGE, READNEXT)                                   \
  {                                                                                \
    const char* bufp_ = lds + (((p) & 3) << 15);                                   \
    _Pragma("unroll")                                                              \
    for (int ni_ = 0; ni_ < 4; ++ni_) bv[ni_] = *(const bf16x8*)(bufp_ + offB[ni_]);\
    if (DOSTAGE) STAGE((p) + 3);                                                   \
    asm volatile("s_waitcnt vmcnt(" #W ")" ::: "memory");                          \
    __builtin_amdgcn_s_barrier();                                                  \
    asm volatile("" ::: "memory");                                                 \
    __builtin_amdgcn_s_setprio(1);                                                 \
    _Pragma("unroll")                                                              \
    for (int mi_ = 0; mi_ < 8; ++mi_)                                              \
      _Pragma("unroll")                                                            \
      for (int ni_ = 0; ni_ < 4; ++ni_)                                            \
        acc[mi_][ni_] =                                                            \
            __builtin_amdgcn_mfma_f32_16x16x32_bf16(AVC[mi_], bv[ni_], acc[mi_][ni_], 0, 0, 0); \
    __builtin_amdgcn_s_setprio(0);                                                 \
    if (READNEXT) {                                                                \
      const char* bufn_ = lds + ((((p) + 1) & 3) << 15);                           \
      _Pragma("unroll")                                                            \
      for (int mi_ = 0; mi_ < 8; ++mi_) AVN[mi_] = *(const bf16x8*)(bufn_ + offA[mi_]); \
    }                                                                              \
    asm volatile("" ::: "memory");                                                 \
    __builtin_amdgcn_s_barrier();                                                  \
  }

  #pragma unroll 1
  for (int p = 0; p < NT - 4; p += 2) {
    PHASE(p, avA, avB, 8, 1, 1);
    PHASE(p + 1, avB, avA, 8, 1, 1);
  }
  PHASE(NT - 4, avA, avB, 8, 1, 1);   // stages NT-1 (last)
  PHASE(NT - 3, avB, avA, 4, 0, 1);
  PHASE(NT - 2, avA, avB, 0, 0, 1);
  PHASE(NT - 1, avB, avA, 0, 0, 0);
#undef PHASE

  // --- epilogue ---
  #pragma unroll
  for (int mi = 0; mi < 8; ++mi) {
    const int r0 = m0 + (wm << 7) + (mi << 4) + (kq << 2);
    #pragma unroll
    for (int ni = 0; ni < 4; ++ni) {
      const int col = n0 + (wn << 6) + (ni << 4) + fr;
      const float bsum = bias1[col] + bias2[col];
      #pragma unroll
      for (int j = 0; j < 4; ++j) {
        const size_t idx = (size_t)(r0 + j) * CO + col;
        float v = acc[mi][ni][j] + bsum;
        if (MODE == 0) {
          outf[idx] = fmaxf(v, 0.f);
        } else if (MODE == 3) {
          float rt = fmaxf(v, 0.f);
          outh[idx] = __float2bfloat16(__bfloat162float(aligh[idx]) * rt);
        } else {
          float m = fmaxf(v, 0.f);
          float z = ztp[idx];
          outf[idx] = (1.f - z) * alig[idx] + z * m;
        }
      }
    }
  }
}

}  // namespace

extern "C" void kernel_launch(void* const* d_in, const int* in_sizes, int n_in,
                              void* d_out, int out_size, void* d_ws, size_t ws_size,
                              hipStream_t stream) {
  const float* curr_F = (const float*)d_in[0];
  const float* prev_F = (const float*)d_in[1];
  const float* prev_M = (const float*)d_in[2];
  const float* Wz_w = (const float*)d_in[3];
  const float* Wz_b = (const float*)d_in[4];
  const float* Wr_w = (const float*)d_in[5];
  const float* Wr_b = (const float*)d_in[6];
  const float* W_w  = (const float*)d_in[7];
  const float* W_b  = (const float*)d_in[8];
  const float* Uz_w = (const float*)d_in[9];
  const float* Uz_b = (const float*)d_in[10];
  const float* Ur_w = (const float*)d_in[11];
  const float* Ur_b = (const float*)d_in[12];
  const float* U_w  = (const float*)d_in[13];
  const float* U_b  = (const float*)d_in[14];
  const int* body   = (const int*)d_in[15];
  float* out = (float*)d_out;

  char* ws = (char*)d_ws;
  const size_t M64 = 1ull << 26;  // 64 MiB
  const size_t M32 = 1ull << 25;  // 32 MiB
  // region0: currF bf16 cl (stays read-only through all GEMMs)
  bf16*  currF_h   = (bf16*)(ws);
  // region1: prevM f32 cl -> later zt f32 cl (prevM dead after align_k)
  float* prevM_cl  = (float*)(ws + M64);
  float* zt        = (float*)(ws + M64);
  float* align_f   = (float*)(ws + 2 * M64);
  bf16*  align_h   = (bf16*)(ws + 3 * M64);
  float* currM_cl  = (float*)(ws + 3 * M64 + M32);   // old wpart slot (64 MiB)
  bf16*  ar_h      = (bf16*)(ws + 4 * M64 + M32);
  char*  wb        = ws + 4 * M64 + 2 * M32;
  bf16* Wz_h = (bf16*)wb;
  bf16* Wr_h = Wz_h + (size_t)CO * CI;
  bf16* W_h  = Wr_h + (size_t)CO * CI;
  bf16* Uz_h = W_h  + (size_t)CO * CI;
  bf16* Ur_h = Uz_h + (size_t)CO * CO;
  bf16* U_h  = Ur_h + (size_t)CO * CO;
  float* prev_nc = (float*)(U_h + (size_t)CO * CO);
  float* invden  = prev_nc + NB * HW;

  // weights -> bf16 (one launch)
  castw6_k<<<dim3((CI * CO) / 1024, 6), 256, 0, stream>>>(
      Wz_w, Wr_w, W_w, Uz_w, Ur_w, U_w, Wz_h, Wr_h, W_h, Uz_h, Ur_h, U_h);

  // prev_nc = sum_c prev_F
  zero_k<<<dim3((NB * HW) / 256), 256, 0, stream>>>(prev_nc, NB * HW);
  nc_sum_k<<<dim3(HW / 256, CI / 128, NB), 256, 0, stream>>>(prev_F, prev_nc);

  // transposes to channels-last
  transpose_k<bf16><<<dim3(CI / 32, HW / 32, NB), 256, 0, stream>>>(curr_F, currF_h, CI, HW);
  transpose_k<float><<<dim3(CO / 32, HW / 32, NB), 256, 0, stream>>>(prev_M, prevM_cl, CO, HW);

  boxinv_k<<<dim3((NB * HW) / 256), 256, 0, stream>>>(prev_nc, invden);
  align_k<<<dim3(NB * HW), 256, 0, stream>>>(prevM_cl, prev_nc, invden, body, align_f, align_h);

  dim3 gg(MTOT / 256, CO / 256);  // (64, 4) = 256 workgroups = 1/CU
  // zt = relu(Wz@curr + Uz@aligned + biases)   [bn_star is a no-op for B=4]
  gemm256<0><<<gg, 512, 0, stream>>>(currF_h, Wz_h, align_h, Uz_h,
                                     Wz_b, Uz_b, nullptr, nullptr, nullptr, zt, nullptr);
  // ar = bf16(aligned * relu(Wr@curr + Ur@aligned + biases))
  gemm256<3><<<gg, 512, 0, stream>>>(currF_h, Wr_h, align_h, Ur_h,
                                     Wr_b, Ur_b, nullptr, nullptr, align_h, nullptr, ar_h);
  // currM = (1-zt)*aligned + zt*relu(W@curr + U@ar + W_b + U_b)
  gemm256<2><<<gg, 512, 0, stream>>>(currF_h, W_h, ar_h, U_h,
                                     W_b, U_b, zt, align_f, nullptr, currM_cl, nullptr);

  // [b,p,o] -> [b,o,p]
  transpose_k<float><<<dim3(HW / 32, CO / 32, NB), 256, 0, stream>>>(currM_cl, out, HW, CO);
}